// Round 7
// baseline (290.407 us; speedup 1.0000x reference)
//
#include <hip/hip_runtime.h>
#include <hip/hip_bf16.h>

#define NTOK 9216   // H*W
#define CCH  256    // C
#define DQK  32     // CQ
#define SSEG 8      // i-split factor (segments of 1152 rows)

typedef __attribute__((ext_vector_type(8))) short short8;
typedef __attribute__((ext_vector_type(4))) float f32x4;
typedef __attribute__((ext_vector_type(16))) float f32x16;
typedef __attribute__((ext_vector_type(2))) unsigned int uint2v;

__device__ __forceinline__ unsigned short f2bf(float x) {
    union { float f; unsigned int u; } v; v.f = x;
    return (unsigned short)((v.u + 0x7FFF + ((v.u >> 16) & 1)) >> 16); // RNE
}
__device__ __forceinline__ float bf2f(unsigned short h) {
    union { unsigned int u; float f; } v; v.u = ((unsigned int)h) << 16; return v.f;
}

#if __has_builtin(__builtin_amdgcn_cvt_pk_bf16_f32)
__device__ __forceinline__ unsigned int pack2bf(float a, float b) {
    auto p = __builtin_amdgcn_cvt_pk_bf16_f32(a, b);   // 1 VALU op (gfx950 HW cvt)
    union { decltype(p) v; unsigned int u; } cv; cv.v = p; return cv.u;
}
#else
__device__ __forceinline__ unsigned int pack2bf(float a, float b) {
    return (unsigned)f2bf(a) | ((unsigned)f2bf(b) << 16);
}
#endif

// scores arrive pre-scaled by log2(e)  ->  P = 2^sc = e^s, raw v_exp_f32
#if __has_builtin(__builtin_amdgcn_exp2f)
#define EXP2(x) __builtin_amdgcn_exp2f(x)
#else
#define EXP2(x) __expf((x) * 0.69314718055994531f)
#endif

// async global->LDS, 16B per lane; LDS dest = wave-uniform base + lane*16
#define GLOAD_LDS16(g, l)                                                     \
    __builtin_amdgcn_global_load_lds(                                         \
        (const __attribute__((address_space(1))) unsigned int*)(g),           \
        (__attribute__((address_space(3))) unsigned int*)(l), 16, 0, 0)

__device__ __forceinline__ f32x16 zero16() {
    f32x16 z;
#pragma unroll
    for (int i = 0; i < 16; ++i) z[i] = 0.f;
    return z;
}

// ---------------- Kernel 0: w -> bf16 ----------------
__global__ __launch_bounds__(256) void wcvt_kernel(
    const float* __restrict__ w, unsigned short* __restrict__ wbf)
{
    const int i = (blockIdx.x * 256 + threadIdx.x) * 4;  // 320*256 = 81920 elems
    f32x4 v = *(const f32x4*)(w + i);
    *(unsigned int*)(wbf + i)     = pack2bf(v[0], v[1]);
    *(unsigned int*)(wbf + i + 2) = pack2bf(v[2], v[3]);
}

// ---------------- Kernel 1: QKV projection via MFMA (validated, ~40 us) ----------------
__global__ __launch_bounds__(256) void qkv_kernel(
    const float* __restrict__ x, const unsigned short* __restrict__ wbf,
    unsigned short* __restrict__ qT, unsigned short* __restrict__ kT,
    unsigned short* __restrict__ vcn)
{
    const int id   = blockIdx.x;      // 1152 = 576 n-tiles x 2 b
    const int b    = id & 1;
    const int n0   = (id >> 1) * 16;
    const int t    = threadIdx.x;
    const int wv   = t >> 6;
    const int lane = t & 63;
    const int l15  = lane & 15;
    const int qd   = lane >> 4;

    const float* xb = x + (size_t)b * CCH * NTOK + n0 + l15;

    f32x4 acc[5];
#pragma unroll
    for (int tt = 0; tt < 5; ++tt) acc[tt] = (f32x4){0.f, 0.f, 0.f, 0.f};

    const unsigned short* wrow = wbf + (size_t)(80 * wv + l15) * CCH + qd * 8;

#pragma unroll
    for (int kk = 0; kk < 8; ++kk) {
        float xe[8];
#pragma unroll
        for (int e = 0; e < 8; ++e)
            xe[e] = xb[(size_t)(32 * kk + 8 * qd + e) * NTOK];
        short8 bfr;
#pragma unroll
        for (int e = 0; e < 8; ++e)
            bfr[e] = (short)f2bf(xe[e]);
#pragma unroll
        for (int tt = 0; tt < 5; ++tt) {
            short8 afr = *(const short8*)(wrow + (size_t)(16 * tt) * CCH + 32 * kk);
            acc[tt] = __builtin_amdgcn_mfma_f32_16x16x32_bf16(afr, bfr, acc[tt], 0, 0, 0);
        }
    }

    const int n = n0 + l15;
    const float L2E = 1.44269504088896f;
#pragma unroll
    for (int tt = 0; tt < 5; ++tt) {
        const int o0l = 80 * wv + 16 * tt + 4 * qd;   // + r, r=0..3
        if (o0l < 32) {
            unsigned short* d = qT + ((size_t)b * NTOK + n) * DQK + o0l;
            *(unsigned int*)d       = pack2bf(acc[tt][0] * L2E, acc[tt][1] * L2E);
            *(unsigned int*)(d + 2) = pack2bf(acc[tt][2] * L2E, acc[tt][3] * L2E);
        } else if (o0l < 64) {
            unsigned short* d = kT + ((size_t)b * NTOK + n) * DQK + (o0l - 32);
            *(unsigned int*)d       = pack2bf(acc[tt][0], acc[tt][1]);
            *(unsigned int*)(d + 2) = pack2bf(acc[tt][2], acc[tt][3]);
        } else {
            unsigned short* d = vcn + ((size_t)b * CCH + (o0l - 64)) * NTOK + n;
            d[0] = f2bf(acc[tt][0]);
            d[(size_t)NTOK] = f2bf(acc[tt][1]);
            d[(size_t)2 * NTOK] = f2bf(acc[tt][2]);
            d[(size_t)3 * NTOK] = f2bf(acc[tt][3]);
        }
    }
}

// ---------------- Kernel 2: flash attention partials (v6: conflict-free LDS) ----------------
// R6 post-mortem: v5's 64B rows made V reads 4-way bank-conflicted (row
// contributes only 64*(row&1) mod 128; 4-slot XOR can't spread 16 lanes over
// 8 slots).  v6 geometry (reads derived conflict-free at quarter-wave level):
//  V: [128 c][64 i] rows = 128 B, slot = i-chunk ^ (c&7)  -> 8 classes x 2
//     lanes (different rows) = free.  (v3-validated read pattern, at v5's
//     halved read count.)
//  Q: [32 rows][64 shorts] rows = 128 B, row = i>>1, byte-in-row =
//     64*(i&1) + 16*(chunk ^ ((i>>1)&3)) -> 8 distinct starts = free
//     (fixes the conflict source v3/v5 shared).
// Register structure (Phase A/B, fits 256) and permlane convention from v5.
__global__ __launch_bounds__(256, 2) void attn_partial_kernel(
    const unsigned short* __restrict__ qT, const unsigned short* __restrict__ kT,
    const unsigned short* __restrict__ vcn,
    unsigned short* __restrict__ Opart, float* __restrict__ lpart)
{
    __shared__ __align__(16) unsigned short Vt[2][128 * 64]; // 2 x 16 KB
    __shared__ __align__(16) unsigned short Qt[2][32 * 64];  // 2 x 4 KB

    const int id    = blockIdx.x;          // 1152 = 72 (jb x b) x 16 combos
    const int combo = id & 15;
    const int s     = combo >> 1;          // i-segment 0..7
    const int cb    = combo & 1;           // c-half 0..1
    const int r     = id >> 4;             // 0..71
    const int jb    = r % 36;
    const int b     = r / 36;

    const int t    = threadIdx.x;
    const int wv   = t >> 6;
    const int lane = t & 63;
    const int l31  = lane & 31;
    const int b5   = lane >> 5;
    const int jw   = jb * 256 + 64 * wv;   // wave's private 64-j slice
    const int c0   = cb * 128;
    const int iBeg = s * (NTOK / SSEG);
    const int iEnd = iBeg + (NTOK / SSEG);

    // resident K B-frags: kf[jg][kd] -> B[k=d=16kd+8b5+e][n=j=jw+32jg+l31]
    short8 kf[2][2];
#pragma unroll
    for (int jg = 0; jg < 2; ++jg)
#pragma unroll
        for (int kd = 0; kd < 2; ++kd)
            kf[jg][kd] = *(const short8*)(kT +
                ((size_t)b * NTOK + jw + 32 * jg + l31) * DQK + 16 * kd + 8 * b5);

    f32x16 acc[2][4]; // O[c = c0+32ct+(reg&3)+8*(reg>>2)+4*b5][j = jw+32jg+l31]
#pragma unroll
    for (int jg = 0; jg < 2; ++jg)
#pragma unroll
        for (int ct = 0; ct < 4; ++ct) acc[jg][ct] = zero16();
    float lw[2] = {0.f, 0.f};

    const unsigned short* vsegb = vcn + ((size_t)b * CCH + c0) * NTOK;
    const unsigned short* qsegb = qT + (size_t)b * NTOK * DQK;

    // stage (sources pre-swizzled; LDS dests linear & wave-uniform):
    //  V: 16 gload_lds (4/wave); lane L -> row rv = 32wv+8g+(L>>3),
    //     slot L&7 holds global i-chunk (L&7)^(rv&7).
    //  Q: 4 gload_lds (1/wave); lane L -> row rq = 8wv+(L>>3), slot L&7:
    //     i = 2rq+((L&7)>>2), d-chunk (L&3)^(rq&3).
    auto stage = [&](int buf, int i0s) {
#pragma unroll
        for (int g = 0; g < 4; ++g) {
            const int rv = 32 * wv + 8 * g + (lane >> 3);
            const unsigned short* src =
                vsegb + (size_t)rv * NTOK + i0s + 8 * ((lane & 7) ^ (rv & 7));
            GLOAD_LDS16(src, &Vt[buf][(32 * wv + 8 * g) * 64]);
        }
        const int rq = 8 * wv + (lane >> 3);
        const int iq = 2 * rq + ((lane & 7) >> 2);
        const int cq = (lane & 3) ^ (rq & 3);
        GLOAD_LDS16(qsegb + (size_t)(i0s + iq) * DQK + 8 * cq,
                    &Qt[buf][(8 * wv) * 64]);
    };

    int cur = 0;
    stage(0, iBeg);
    __syncthreads();   // drains staging vmcnt

#pragma unroll 1
    for (int i0 = iBeg; i0 < iEnd; i0 += 64) {
        const int inext = (i0 + 64 < iEnd) ? i0 + 64 : iBeg; // dummy on last iter
        stage(cur ^ 1, inext);   // issue BEFORE compute; drains at the barrier

#pragma unroll
        for (int it = 0; it < 2; ++it) {
            // ---- Phase A: QK + exp for BOTH jg; sc dies into pk0/pk1 ----
            // af: A[m=i=32it+l31][k=16kd+8b5+e]; Qt row = i>>1 = 16it+(l31>>1)
            const int qr   = 16 * it + (l31 >> 1);
            const int qoff = qr * 64 + 32 * (l31 & 1);
            const int qswz = (l31 >> 1) & 3;
            short8 af0 = *(const short8*)&Qt[cur][qoff + 8 * ((b5) ^ qswz)];
            short8 af1 = *(const short8*)&Qt[cur][qoff + 8 * ((2 + b5) ^ qswz)];

            unsigned int pk0[8], pk1[8];
            {
                __builtin_amdgcn_s_setprio(1);
                f32x16 sc0 = __builtin_amdgcn_mfma_f32_32x32x16_bf16(af0, kf[0][0], zero16(), 0, 0, 0);
                sc0 = __builtin_amdgcn_mfma_f32_32x32x16_bf16(af1, kf[0][1], sc0, 0, 0, 0);
                f32x16 sc1 = __builtin_amdgcn_mfma_f32_32x32x16_bf16(af0, kf[1][0], zero16(), 0, 0, 0);
                sc1 = __builtin_amdgcn_mfma_f32_32x32x16_bf16(af1, kf[1][1], sc1, 0, 0, 0);
                __builtin_amdgcn_s_setprio(0);
                float ls0 = 0.f, ls1 = 0.f;
#pragma unroll
                for (int w = 0; w < 8; ++w) {
                    float p0 = EXP2(sc0[2 * w]);
                    float p1 = EXP2(sc0[2 * w + 1]);
                    ls0 += p0 + p1;
                    pk0[w] = pack2bf(p0, p1);
                }
#pragma unroll
                for (int w = 0; w < 8; ++w) {
                    float p0 = EXP2(sc1[2 * w]);
                    float p1 = EXP2(sc1[2 * w + 1]);
                    ls1 += p0 + p1;
                    pk1[w] = pack2bf(p0, p1);
                }
                lw[0] += ls0;
                lw[1] += ls1;
            }

            // ---- Phase B: PV; vf loaded just-in-time per kc2 ----
#pragma unroll
            for (int kc2 = 0; kc2 < 2; ++kc2) {
                short8 vf[4];
#pragma unroll
                for (int ct = 0; ct < 4; ++ct)
                    vf[ct] = *(const short8*)&Vt[cur][
                        (32 * ct + l31) * 64 +
                        8 * ((4 * it + 2 * kc2 + b5) ^ (l31 & 7))];

                const int base = 4 * kc2;
                union { unsigned int u[4]; short8 s8; } bu0, bu1;
#if __has_builtin(__builtin_amdgcn_permlane32_swap)
                // ISA: swap(VDST,VSRC) exchanges VDST lanes 32-63 with
                // VSRC lanes 0-31 (validated R5).
                {
                    uint2v r1 = __builtin_amdgcn_permlane32_swap(
                        pk0[base], pk0[base + 2], false, false);
                    uint2v r2 = __builtin_amdgcn_permlane32_swap(
                        pk0[base + 1], pk0[base + 3], false, false);
                    bu0.u[0] = r1[0]; bu0.u[1] = r2[0];
                    bu0.u[2] = r1[1]; bu0.u[3] = r2[1];
                    uint2v r3 = __builtin_amdgcn_permlane32_swap(
                        pk1[base], pk1[base + 2], false, false);
                    uint2v r4 = __builtin_amdgcn_permlane32_swap(
                        pk1[base + 1], pk1[base + 3], false, false);
                    bu1.u[0] = r3[0]; bu1.u[1] = r4[0];
                    bu1.u[2] = r3[1]; bu1.u[3] = r4[1];
                }
#else
                {
                    unsigned int m1 = b5 ? pk0[base]     : pk0[base + 2];
                    unsigned int m2 = b5 ? pk0[base + 1] : pk0[base + 3];
                    unsigned int x1 = __shfl_xor(m1, 32);
                    unsigned int x2 = __shfl_xor(m2, 32);
                    bu0.u[0] = b5 ? x1 : pk0[base];
                    bu0.u[1] = b5 ? x2 : pk0[base + 1];
                    bu0.u[2] = b5 ? pk0[base + 2] : x1;
                    bu0.u[3] = b5 ? pk0[base + 3] : x2;
                    unsigned int m3 = b5 ? pk1[base]     : pk1[base + 2];
                    unsigned int m4 = b5 ? pk1[base + 1] : pk1[base + 3];
                    unsigned int x3 = __shfl_xor(m3, 32);
                    unsigned int x4 = __shfl_xor(m4, 32);
                    bu1.u[0] = b5 ? x3 : pk1[base];
                    bu1.u[1] = b5 ? x4 : pk1[base + 1];
                    bu1.u[2] = b5 ? pk1[base + 2] : x3;
                    bu1.u[3] = b5 ? pk1[base + 3] : x4;
                }
#endif
                __builtin_amdgcn_s_setprio(1);
#pragma unroll
                for (int ct = 0; ct < 4; ++ct)
                    acc[0][ct] = __builtin_amdgcn_mfma_f32_32x32x16_bf16(
                        vf[ct], bu0.s8, acc[0][ct], 0, 0, 0);
#pragma unroll
                for (int ct = 0; ct < 4; ++ct)
                    acc[1][ct] = __builtin_amdgcn_mfma_f32_32x32x16_bf16(
                        vf[ct], bu1.s8, acc[1][ct], 0, 0, 0);
                __builtin_amdgcn_s_setprio(0);
            }
        }
        __syncthreads();   // next tile staged & current reads done
        cur ^= 1;
    }

    // l partial: lane pair (L, L^32) covers all 32 rows per tile
    if (cb == 0) {
        float lt0 = lw[0] + __shfl_xor(lw[0], 32);
        float lt1 = lw[1] + __shfl_xor(lw[1], 32);
        if (b5 == 0) {
            lpart[(size_t)(s * 2 + b) * NTOK + jw + l31]      = lt0;
            lpart[(size_t)(s * 2 + b) * NTOK + jw + 32 + l31] = lt1;
        }
    }

    // store raw partial O as bf16; lanes 0-31 cover 32 contiguous j (64B line)
#pragma unroll
    for (int jg = 0; jg < 2; ++jg)
#pragma unroll
        for (int ct = 0; ct < 4; ++ct)
#pragma unroll
            for (int w = 0; w < 16; ++w) {
                const int c = c0 + 32 * ct + (w & 3) + 8 * (w >> 2) + 4 * b5;
                Opart[((size_t)(s * 2 + b) * CCH + c) * NTOK + jw + 32 * jg + l31] =
                    f2bf(acc[jg][ct][w]);
            }
}

// ---------------- Kernel 3: reduce partials + normalize + residual ----------------
__global__ __launch_bounds__(256) void reduce_kernel(
    const unsigned short* __restrict__ Opart, const float* __restrict__ lpart,
    const float* __restrict__ x, const float* __restrict__ gamma,
    float* __restrict__ out)
{
    const size_t flat = ((size_t)blockIdx.x * 256 + threadIdx.x) * 4;
    const int j = (int)(flat % NTOK);
    const int b = (int)(flat / ((size_t)CCH * NTOK));
    const size_t inb = flat - (size_t)b * CCH * NTOK;  // c*NTOK + j

    f32x4 o = {0.f, 0.f, 0.f, 0.f};
    f32x4 l = {0.f, 0.f, 0.f, 0.f};
#pragma unroll
    for (int s = 0; s < SSEG; ++s) {
        const size_t plane = (size_t)(s * 2 + b) * CCH * NTOK;
        unsigned long long ov = *(const unsigned long long*)(Opart + plane + inb);
        f32x4 lv = *(const f32x4*)(lpart + (size_t)(s * 2 + b) * NTOK + j);
        o[0] += bf2f((unsigned short)(ov));
        o[1] += bf2f((unsigned short)(ov >> 16));
        o[2] += bf2f((unsigned short)(ov >> 32));
        o[3] += bf2f((unsigned short)(ov >> 48));
        l[0] += lv[0]; l[1] += lv[1]; l[2] += lv[2]; l[3] += lv[3];
    }
    const float g = gamma[0];
    f32x4 xv = *(const f32x4*)(x + flat);
    f32x4 rr;
    rr[0] = g * o[0] / l[0] + xv[0];
    rr[1] = g * o[1] / l[1] + xv[1];
    rr[2] = g * o[2] / l[2] + xv[2];
    rr[3] = g * o[3] / l[3] + xv[3];
    *(f32x4*)(out + flat) = rr;
}

extern "C" void kernel_launch(void* const* d_in, const int* in_sizes, int n_in,
                              void* d_out, int out_size, void* d_ws, size_t ws_size,
                              hipStream_t stream) {
    const float* x     = (const float*)d_in[0];
    const float* w     = (const float*)d_in[1];
    const float* gamma = (const float*)d_in[2];
    float* out = (float*)d_out;

    unsigned short* qT  = (unsigned short*)d_ws;          // 1.18 MB
    unsigned short* kT  = qT + (size_t)2 * NTOK * DQK;    // 1.18 MB
    unsigned short* vcn = kT + (size_t)2 * NTOK * DQK;    // 9.44 MB
    unsigned short* Opart = vcn + (size_t)2 * CCH * NTOK; // 8*2*256*9216 bf16 = 75.5 MB
    float* lpart = (float*)(Opart + (size_t)SSEG * 2 * CCH * NTOK); // 590 KB
    unsigned short* wbf = (unsigned short*)(lpart + (size_t)SSEG * 2 * NTOK); // 164 KB

    wcvt_kernel<<<80, 256, 0, stream>>>(w, wbf);

    qkv_kernel<<<1152, 256, 0, stream>>>(x, wbf, qT, kT, vcn);

    attn_partial_kernel<<<1152, 256, 0, stream>>>(qT, kT, vcn, Opart, lpart);

    reduce_kernel<<<(unsigned)((size_t)2 * CCH * NTOK / 4 / 256), 256, 0, stream>>>(
        Opart, lpart, x, gamma, out);
}

// Round 8
// 247.752 us; speedup vs baseline: 1.1722x; 1.1722x over previous
//
#include <hip/hip_runtime.h>
#include <hip/hip_bf16.h>

#define NTOK 9216   // H*W
#define CCH  256    // C
#define DQK  32     // CQ
#define SSEG 8      // i-split factor (segments of 1152 rows)

typedef __attribute__((ext_vector_type(8))) short short8;
typedef __attribute__((ext_vector_type(4))) float f32x4;
typedef __attribute__((ext_vector_type(16))) float f32x16;
typedef __attribute__((ext_vector_type(2))) unsigned int uint2v;

__device__ __forceinline__ unsigned short f2bf(float x) {
    union { float f; unsigned int u; } v; v.f = x;
    return (unsigned short)((v.u + 0x7FFF + ((v.u >> 16) & 1)) >> 16); // RNE
}
__device__ __forceinline__ float bf2f(unsigned short h) {
    union { unsigned int u; float f; } v; v.u = ((unsigned int)h) << 16; return v.f;
}

#if __has_builtin(__builtin_amdgcn_cvt_pk_bf16_f32)
__device__ __forceinline__ unsigned int pack2bf(float a, float b) {
    auto p = __builtin_amdgcn_cvt_pk_bf16_f32(a, b);   // 1 VALU op (gfx950 HW cvt)
    union { decltype(p) v; unsigned int u; } cv; cv.v = p; return cv.u;
}
#else
__device__ __forceinline__ unsigned int pack2bf(float a, float b) {
    return (unsigned)f2bf(a) | ((unsigned)f2bf(b) << 16);
}
#endif

// scores arrive pre-scaled by log2(e)  ->  P = 2^sc = e^s, raw v_exp_f32
#if __has_builtin(__builtin_amdgcn_exp2f)
#define EXP2(x) __builtin_amdgcn_exp2f(x)
#else
#define EXP2(x) __expf((x) * 0.69314718055994531f)
#endif

// async global->LDS, 16B per lane; LDS dest = wave-uniform base + lane*16
#define GLOAD_LDS16(g, l)                                                     \
    __builtin_amdgcn_global_load_lds(                                         \
        (const __attribute__((address_space(1))) unsigned int*)(g),           \
        (__attribute__((address_space(3))) unsigned int*)(l), 16, 0, 0)

__device__ __forceinline__ f32x16 zero16() {
    f32x16 z;
#pragma unroll
    for (int i = 0; i < 16; ++i) z[i] = 0.f;
    return z;
}

// ---------------- Kernel 0: w -> bf16 ----------------
__global__ __launch_bounds__(256) void wcvt_kernel(
    const float* __restrict__ w, unsigned short* __restrict__ wbf)
{
    const int i = (blockIdx.x * 256 + threadIdx.x) * 4;  // 320*256 = 81920 elems
    f32x4 v = *(const f32x4*)(w + i);
    *(unsigned int*)(wbf + i)     = pack2bf(v[0], v[1]);
    *(unsigned int*)(wbf + i + 2) = pack2bf(v[2], v[3]);
}

// ---------------- Kernel 1: QKV projection via MFMA (validated, ~40 us) ----------------
__global__ __launch_bounds__(256) void qkv_kernel(
    const float* __restrict__ x, const unsigned short* __restrict__ wbf,
    unsigned short* __restrict__ qT, unsigned short* __restrict__ kT,
    unsigned short* __restrict__ vcn)
{
    const int id   = blockIdx.x;      // 1152 = 576 n-tiles x 2 b
    const int b    = id & 1;
    const int n0   = (id >> 1) * 16;
    const int t    = threadIdx.x;
    const int wv   = t >> 6;
    const int lane = t & 63;
    const int l15  = lane & 15;
    const int qd   = lane >> 4;

    const float* xb = x + (size_t)b * CCH * NTOK + n0 + l15;

    f32x4 acc[5];
#pragma unroll
    for (int tt = 0; tt < 5; ++tt) acc[tt] = (f32x4){0.f, 0.f, 0.f, 0.f};

    const unsigned short* wrow = wbf + (size_t)(80 * wv + l15) * CCH + qd * 8;

#pragma unroll
    for (int kk = 0; kk < 8; ++kk) {
        float xe[8];
#pragma unroll
        for (int e = 0; e < 8; ++e)
            xe[e] = xb[(size_t)(32 * kk + 8 * qd + e) * NTOK];
        short8 bfr;
#pragma unroll
        for (int e = 0; e < 8; ++e)
            bfr[e] = (short)f2bf(xe[e]);
#pragma unroll
        for (int tt = 0; tt < 5; ++tt) {
            short8 afr = *(const short8*)(wrow + (size_t)(16 * tt) * CCH + 32 * kk);
            acc[tt] = __builtin_amdgcn_mfma_f32_16x16x32_bf16(afr, bfr, acc[tt], 0, 0, 0);
        }
    }

    const int n = n0 + l15;
    const float L2E = 1.44269504088896f;
#pragma unroll
    for (int tt = 0; tt < 5; ++tt) {
        const int o0l = 80 * wv + 16 * tt + 4 * qd;   // + r, r=0..3
        if (o0l < 32) {
            unsigned short* d = qT + ((size_t)b * NTOK + n) * DQK + o0l;
            *(unsigned int*)d       = pack2bf(acc[tt][0] * L2E, acc[tt][1] * L2E);
            *(unsigned int*)(d + 2) = pack2bf(acc[tt][2] * L2E, acc[tt][3] * L2E);
        } else if (o0l < 64) {
            unsigned short* d = kT + ((size_t)b * NTOK + n) * DQK + (o0l - 32);
            *(unsigned int*)d       = pack2bf(acc[tt][0], acc[tt][1]);
            *(unsigned int*)(d + 2) = pack2bf(acc[tt][2], acc[tt][3]);
        } else {
            unsigned short* d = vcn + ((size_t)b * CCH + (o0l - 64)) * NTOK + n;
            d[0] = f2bf(acc[tt][0]);
            d[(size_t)NTOK] = f2bf(acc[tt][1]);
            d[(size_t)2 * NTOK] = f2bf(acc[tt][2]);
            d[(size_t)3 * NTOK] = f2bf(acc[tt][3]);
        }
    }
}

// ---------------- Kernel 2: flash attention partials (v8) ----------------
// Arc post-mortem (v3=168 3w/SIMD, v5=178 2w, v6=199 2w): pipe-busy times are
// IDENTICAL across variants (MFMA ~46us, VALU ~71us); the ranking variable is
// occupancy — acc[2][4]=256 unified regs forces 2 waves/SIMD and the stall
// can't be hidden.  v8 = all validated pieces at v3's occupancy:
//  - j=32/wave, c=128/block, grid 2304 (9 blocks/CU, good tail balance)
//  - acc[4] f32x16 = 64 AGPR, ~85 VGPR -> ~150 regs -> 3 waves/SIMD (256,3)
//  - register-P via permlane32_swap (R5-validated), no P-LDS, ONE barrier/step
//  - conflict-free V[128c][64i]/Q[32][64] slot-XOR layouts (v6-validated)
// vs v3 this deletes: P LDS round-trip, one barrier/step, 1.86e7 conflicts.
__global__ __launch_bounds__(256, 3) void attn_partial_kernel(
    const unsigned short* __restrict__ qT, const unsigned short* __restrict__ kT,
    const unsigned short* __restrict__ vcn,
    unsigned short* __restrict__ Opart, float* __restrict__ lpart)
{
    __shared__ __align__(16) unsigned short Vt[2][128 * 64]; // 2 x 16 KB
    __shared__ __align__(16) unsigned short Qt[2][32 * 64];  // 2 x 4 KB

    const int id    = blockIdx.x;          // 2304 = 144 (jb x b) x 16 combos
    const int combo = id & 15;             // id&7 = XCD: V-chunk L2 locality
    const int s     = combo >> 1;          // i-segment 0..7
    const int cb    = combo & 1;           // c-half 0..1
    const int r     = id >> 4;             // 0..143
    const int jb    = r % 72;
    const int b     = r / 72;

    const int t    = threadIdx.x;
    const int wv   = t >> 6;
    const int lane = t & 63;
    const int l31  = lane & 31;
    const int b5   = lane >> 5;
    const int jw   = jb * 128 + 32 * wv;   // wave's private 32-j slice
    const int c0   = cb * 128;
    const int iBeg = s * (NTOK / SSEG);
    const int iEnd = iBeg + (NTOK / SSEG);

    // resident K B-frags: kf[kd] -> B[k=d=16kd+8b5+e][n=j=jw+l31]
    short8 kf[2];
#pragma unroll
    for (int kd = 0; kd < 2; ++kd)
        kf[kd] = *(const short8*)(kT +
            ((size_t)b * NTOK + jw + l31) * DQK + 16 * kd + 8 * b5);

    f32x16 acc[4]; // O[c = c0+32ct+(w&3)+8*(w>>2)+4*b5][j = jw+l31]
#pragma unroll
    for (int ct = 0; ct < 4; ++ct) acc[ct] = zero16();
    float lw = 0.f;

    const unsigned short* vsegb = vcn + ((size_t)b * CCH + c0) * NTOK;
    const unsigned short* qsegb = qT + (size_t)b * NTOK * DQK;

    // stage (sources pre-swizzled; LDS dests linear & wave-uniform):
    //  V: 16 gload_lds (4/wave); lane L -> row rv = 32wv+8g+(L>>3),
    //     slot L&7 holds global i-chunk (L&7)^(rv&7).
    //  Q: 4 gload_lds (1/wave); lane L -> row rq = 8wv+(L>>3), slot L&7:
    //     i = 2rq+((L&7)>>2), d-chunk (L&3)^(rq&3).
    auto stage = [&](int buf, int i0s) {
#pragma unroll
        for (int g = 0; g < 4; ++g) {
            const int rv = 32 * wv + 8 * g + (lane >> 3);
            const unsigned short* src =
                vsegb + (size_t)rv * NTOK + i0s + 8 * ((lane & 7) ^ (rv & 7));
            GLOAD_LDS16(src, &Vt[buf][(32 * wv + 8 * g) * 64]);
        }
        const int rq = 8 * wv + (lane >> 3);
        const int iq = 2 * rq + ((lane & 7) >> 2);
        const int cq = (lane & 3) ^ (rq & 3);
        GLOAD_LDS16(qsegb + (size_t)(i0s + iq) * DQK + 8 * cq,
                    &Qt[buf][(8 * wv) * 64]);
    };

    int cur = 0;
    stage(0, iBeg);
    __syncthreads();   // drains staging vmcnt

#pragma unroll 1
    for (int i0 = iBeg; i0 < iEnd; i0 += 64) {
        const int inext = (i0 + 64 < iEnd) ? i0 + 64 : iBeg; // dummy on last iter
        stage(cur ^ 1, inext);   // issue BEFORE compute; drains at the barrier

#pragma unroll
        for (int it = 0; it < 2; ++it) {
            // ---- Phase A: QK + exp; sc dies into pk ----
            // af: A[m=i=32it+l31][k=16kd+8b5+e]; Qt row = i>>1 = 16it+(l31>>1)
            const int qoff = (16 * it + (l31 >> 1)) * 64 + 32 * (l31 & 1);
            const int qswz = (l31 >> 1) & 3;
            short8 af0 = *(const short8*)&Qt[cur][qoff + 8 * ((b5) ^ qswz)];
            short8 af1 = *(const short8*)&Qt[cur][qoff + 8 * ((2 + b5) ^ qswz)];

            unsigned int pk[8];
            {
                __builtin_amdgcn_s_setprio(1);
                f32x16 sc = __builtin_amdgcn_mfma_f32_32x32x16_bf16(af0, kf[0], zero16(), 0, 0, 0);
                sc = __builtin_amdgcn_mfma_f32_32x32x16_bf16(af1, kf[1], sc, 0, 0, 0);
                __builtin_amdgcn_s_setprio(0);
                float ls = 0.f;
#pragma unroll
                for (int w = 0; w < 8; ++w) {
                    float p0 = EXP2(sc[2 * w]);
                    float p1 = EXP2(sc[2 * w + 1]);
                    ls += p0 + p1;
                    pk[w] = pack2bf(p0, p1);
                }
                lw += ls;
            }

            // ---- Phase B: PV; vf loaded just-in-time per kc2 ----
#pragma unroll
            for (int kc2 = 0; kc2 < 2; ++kc2) {
                short8 vf[4];
#pragma unroll
                for (int ct = 0; ct < 4; ++ct)
                    vf[ct] = *(const short8*)&Vt[cur][
                        (32 * ct + l31) * 64 +
                        8 * ((4 * it + 2 * kc2 + b5) ^ (l31 & 7))];

                const int base = 4 * kc2;
                union { unsigned int u[4]; short8 s8; } bu;
#if __has_builtin(__builtin_amdgcn_permlane32_swap)
                // ISA: swap(VDST,VSRC) exchanges VDST lanes 32-63 with
                // VSRC lanes 0-31 (validated R5).
                {
                    uint2v r1 = __builtin_amdgcn_permlane32_swap(
                        pk[base], pk[base + 2], false, false);
                    uint2v r2 = __builtin_amdgcn_permlane32_swap(
                        pk[base + 1], pk[base + 3], false, false);
                    bu.u[0] = r1[0]; bu.u[1] = r2[0];
                    bu.u[2] = r1[1]; bu.u[3] = r2[1];
                }
#else
                {
                    unsigned int m1 = b5 ? pk[base]     : pk[base + 2];
                    unsigned int m2 = b5 ? pk[base + 1] : pk[base + 3];
                    unsigned int x1 = __shfl_xor(m1, 32);
                    unsigned int x2 = __shfl_xor(m2, 32);
                    bu.u[0] = b5 ? x1 : pk[base];
                    bu.u[1] = b5 ? x2 : pk[base + 1];
                    bu.u[2] = b5 ? pk[base + 2] : x1;
                    bu.u[3] = b5 ? pk[base + 3] : x2;
                }
#endif
                __builtin_amdgcn_s_setprio(1);
#pragma unroll
                for (int ct = 0; ct < 4; ++ct)
                    acc[ct] = __builtin_amdgcn_mfma_f32_32x32x16_bf16(
                        vf[ct], bu.s8, acc[ct], 0, 0, 0);
                __builtin_amdgcn_s_setprio(0);
            }
        }
        __syncthreads();   // next tile staged & current reads done
        cur ^= 1;
    }

    // l partial: lane pair (L, L^32) covers all 32 rows per tile
    if (cb == 0) {
        float lt = lw + __shfl_xor(lw, 32);
        if (b5 == 0)
            lpart[(size_t)(s * 2 + b) * NTOK + jw + l31] = lt;
    }

    // store raw partial O as bf16; lanes 0-31 cover 32 contiguous j (64B line)
#pragma unroll
    for (int ct = 0; ct < 4; ++ct)
#pragma unroll
        for (int w = 0; w < 16; ++w) {
            const int c = c0 + 32 * ct + (w & 3) + 8 * (w >> 2) + 4 * b5;
            Opart[((size_t)(s * 2 + b) * CCH + c) * NTOK + jw + l31] =
                f2bf(acc[ct][w]);
        }
}

// ---------------- Kernel 3: reduce partials + normalize + residual ----------------
__global__ __launch_bounds__(256) void reduce_kernel(
    const unsigned short* __restrict__ Opart, const float* __restrict__ lpart,
    const float* __restrict__ x, const float* __restrict__ gamma,
    float* __restrict__ out)
{
    const size_t flat = ((size_t)blockIdx.x * 256 + threadIdx.x) * 4;
    const int j = (int)(flat % NTOK);
    const int b = (int)(flat / ((size_t)CCH * NTOK));
    const size_t inb = flat - (size_t)b * CCH * NTOK;  // c*NTOK + j

    f32x4 o = {0.f, 0.f, 0.f, 0.f};
    f32x4 l = {0.f, 0.f, 0.f, 0.f};
#pragma unroll
    for (int s = 0; s < SSEG; ++s) {
        const size_t plane = (size_t)(s * 2 + b) * CCH * NTOK;
        unsigned long long ov = *(const unsigned long long*)(Opart + plane + inb);
        f32x4 lv = *(const f32x4*)(lpart + (size_t)(s * 2 + b) * NTOK + j);
        o[0] += bf2f((unsigned short)(ov));
        o[1] += bf2f((unsigned short)(ov >> 16));
        o[2] += bf2f((unsigned short)(ov >> 32));
        o[3] += bf2f((unsigned short)(ov >> 48));
        l[0] += lv[0]; l[1] += lv[1]; l[2] += lv[2]; l[3] += lv[3];
    }
    const float g = gamma[0];
    f32x4 xv = *(const f32x4*)(x + flat);
    f32x4 rr;
    rr[0] = g * o[0] / l[0] + xv[0];
    rr[1] = g * o[1] / l[1] + xv[1];
    rr[2] = g * o[2] / l[2] + xv[2];
    rr[3] = g * o[3] / l[3] + xv[3];
    *(f32x4*)(out + flat) = rr;
}

extern "C" void kernel_launch(void* const* d_in, const int* in_sizes, int n_in,
                              void* d_out, int out_size, void* d_ws, size_t ws_size,
                              hipStream_t stream) {
    const float* x     = (const float*)d_in[0];
    const float* w     = (const float*)d_in[1];
    const float* gamma = (const float*)d_in[2];
    float* out = (float*)d_out;

    unsigned short* qT  = (unsigned short*)d_ws;          // 1.18 MB
    unsigned short* kT  = qT + (size_t)2 * NTOK * DQK;    // 1.18 MB
    unsigned short* vcn = kT + (size_t)2 * NTOK * DQK;    // 9.44 MB
    unsigned short* Opart = vcn + (size_t)2 * CCH * NTOK; // 8*2*256*9216 bf16 = 75.5 MB
    float* lpart = (float*)(Opart + (size_t)SSEG * 2 * CCH * NTOK); // 590 KB
    unsigned short* wbf = (unsigned short*)(lpart + (size_t)SSEG * 2 * NTOK); // 164 KB

    wcvt_kernel<<<80, 256, 0, stream>>>(w, wbf);

    qkv_kernel<<<1152, 256, 0, stream>>>(x, wbf, qT, kT, vcn);

    attn_partial_kernel<<<2304, 256, 0, stream>>>(qT, kT, vcn, Opart, lpart);

    reduce_kernel<<<(unsigned)((size_t)2 * CCH * NTOK / 4 / 256), 256, 0, stream>>>(
        Opart, lpart, x, gamma, out);
}